// Round 11
// baseline (560.422 us; speedup 1.0000x reference)
//
#include <hip/hip_runtime.h>
#include <math.h>

#define DEV static __device__ __forceinline__

// ---------------- 4-qubit real-amplitude circuit helpers ----------------
template <int W>
DEV void q_ry(float s[16], float th) {
  float c = cosf(th * 0.5f), sn = sinf(th * 0.5f);
  constexpr int m = 8 >> W;
#pragma unroll
  for (int i = 0; i < 16; ++i) {
    if (!(i & m)) {
      float a = s[i], b = s[i | m];
      s[i] = c * a - sn * b;
      s[i | m] = sn * a + c * b;
    }
  }
}
template <int C, int T>
DEV void q_cnot(float s[16]) {
  constexpr int mc = 8 >> C, mt = 8 >> T;
#pragma unroll
  for (int i = 0; i < 16; ++i) {
    if ((i & mc) && !(i & mt)) {
      float t = s[i]; s[i] = s[i | mt]; s[i | mt] = t;
    }
  }
}
template <int W>
DEV float q_mz(const float s[16]) {
  constexpr int m = 8 >> W;
  float p = 0.f;
#pragma unroll
  for (int i = 0; i < 16; ++i) p += (i & m) ? -s[i] * s[i] : s[i] * s[i];
  return p;
}
DEV void q_layer(float s[16], const float* __restrict__ th) {
  q_ry<0>(s, th[0]); q_cnot<0, 1>(s);
  q_ry<1>(s, th[1]); q_cnot<1, 2>(s);
  q_ry<2>(s, th[2]); q_cnot<2, 3>(s);
  q_ry<3>(s, th[3]); q_cnot<3, 0>(s);
}

// ---------------- weight reorder pre-kernel ----------------
// wre1[(ci*5+ky)*30 + kx*6 + co] = c1w[co][ci][ky][kx]   (450)
// wre2[(ci*3+ky)*45 + kx*15 + co] = c2w[co][ci][ky][kx]  (810)
__global__ void k_wre(const float* __restrict__ c1w, const float* __restrict__ c2w,
                      float* __restrict__ wre1, float* __restrict__ wre2) {
  int t = blockIdx.x * 256 + threadIdx.x;
  if (t < 450) {
    int g = t / 30, rem = t % 30;
    int ci = g / 5, ky = g % 5, kx = rem / 6, co = rem % 6;
    wre1[t] = c1w[co * 75 + ci * 25 + ky * 5 + kx];
  }
  if (t < 810) {
    int g = t / 45, rem = t % 45;
    int ci = g / 3, ky = g % 3, kx = rem / 15, co = rem % 15;
    wre2[t] = c2w[co * 54 + ci * 9 + ky * 3 + kx];
  }
}

// ---------------- conv1 (5x5 s2 p1, 3->6) + relu + pool(2x2 s1) ----------------
// v6: thread = (conv-row, 3-col seg), ALL 6 channels per thread.
// x: (128,3,249,249) -> pooled out: (128,6,123,123)
__global__ __launch_bounds__(256, 4) void k_conv1(const float* __restrict__ x,
                                                  const float* __restrict__ wre1,
                                                  const float* __restrict__ bia,
                                                  float* __restrict__ out) {
  __shared__ float smem[9920];                   // 3*87*38 + 2 pad = 39.7 KB
  float (*ct)[42][19] = (float (*)[42][19])smem; // conv-subtile view (aliases xs)
  int b = blockIdx.z;
  int PY0 = blockIdx.y * 41, PX0 = blockIdx.x * 16;
  int iy0 = PY0 * 2 - 1, ix0 = PX0 * 2 - 1;
  int tid = threadIdx.x;
  const float* xb = x + (size_t)b * 186003;  // 3*249*249
#pragma unroll
  for (int s = 0; s < 39; ++s) {
    int idx = s * 256 + tid;
    bool ok = idx < 9918;
    int ci = idx / 3306, rem = idx - ci * 3306;
    int rr = rem / 38, cc = rem - rr * 38;
    int iy = iy0 + rr, ix = ix0 + cc;
    float v = 0.f;
    if (ok && cc < 37 && (unsigned)iy < 249u && (unsigned)ix < 249u)
      v = xb[ci * 62001 + iy * 249 + ix];
    if (ok) smem[idx] = v;
  }
  __syncthreads();
  int r = tid / 6, seg = tid - 6 * (tid / 6);   // 42 rows x 6 segs = 252
  float acc[6][3];
  if (tid < 252) {
#pragma unroll
    for (int co = 0; co < 6; ++co) {
      float bv = bia[co];
#pragma unroll
      for (int c = 0; c < 3; ++c) acc[co][c] = bv;
    }
#pragma unroll
    for (int ci = 0; ci < 3; ++ci)
#pragma unroll
      for (int ky = 0; ky < 5; ++ky) {
        const float* xrow = &smem[(ci * 87 + 2 * r + ky) * 38 + 6 * seg];
        float xv[10];
#pragma unroll
        for (int j = 0; j < 5; ++j) {            // 5x ds_read_b64
          float2 t2 = *reinterpret_cast<const float2*>(&xrow[2 * j]);
          xv[2 * j] = t2.x; xv[2 * j + 1] = t2.y;
        }
        const float* wp = wre1 + (ci * 5 + ky) * 30;  // uniform -> s_load
        float wr[30];
#pragma unroll
        for (int j = 0; j < 30; ++j) wr[j] = wp[j];
#pragma unroll
        for (int c = 0; c < 3; ++c)
#pragma unroll
          for (int kx = 0; kx < 5; ++kx)
#pragma unroll
            for (int co = 0; co < 6; ++co)
              acc[co][c] += xv[2 * c + kx] * wr[kx * 6 + co];
      }
  }
  __syncthreads();                          // xs reads complete
  if (tid < 252) {
#pragma unroll
    for (int co = 0; co < 6; ++co)
#pragma unroll
      for (int c = 0; c < 3; ++c)
        if (3 * seg + c < 17) ct[co][r][3 * seg + c] = acc[co][c];
  }
  __syncthreads();
#pragma unroll
  for (int co2 = 0; co2 < 6; ++co2) {
    for (int j = tid; j < 41 * 16; j += 256) {
      int pr = j >> 4, pc = j & 15;
      int px = PX0 + pc;
      if (px < 123) {
        float m = fmaxf(fmaxf(ct[co2][pr][pc], ct[co2][pr][pc + 1]),
                        fmaxf(ct[co2][pr + 1][pc], ct[co2][pr + 1][pc + 1]));
        out[((size_t)(b * 6 + co2) * 123 + PY0 + pr) * 123 + px] = fmaxf(m, 0.f);
      }
    }
  }
}

// ---------------- conv2 (3x3 s2 p1, 6->15) + relu + pool ----------------
// v4: co split into 2 groups (8+7), group loop OUTER with its own staging
// cycle -> acc[NCO][3] <= 24 regs, no spill. Template-static indices.
// in: (128,6,123,123) -> h: (128, 15*61*61=55815)
template <int CO0, int NCO>
DEV void conv2_group(const float* __restrict__ ib, const float* __restrict__ wre2,
                     const float* __restrict__ bia, float* __restrict__ out,
                     float* smem, int b, int CY0, int CX0, int PRN,
                     int r, int seg, int tid) {
  float (*ct)[32][17] = (float (*)[32][17])smem;
  int IY0 = 2 * CY0 - 1, IX0 = 2 * CX0 - 1;
  float acc[NCO][3];
#pragma unroll
  for (int j = 0; j < NCO; ++j) {
    float bv = bia[CO0 + j];
#pragma unroll
    for (int c = 0; c < 3; ++c) acc[j][c] = bv;
  }
#pragma unroll
  for (int phase = 0; phase < 2; ++phase) {
    __syncthreads();                       // prior xs/ct consumers done
#pragma unroll
    for (int s = 0; s < 28; ++s) {         // stage 3 ci: 3*65*36 = 7020
      int idx = s * 256 + tid;
      bool ok = idx < 7020;
      int cil = idx / 2340, rem = idx - cil * 2340;
      int rr = rem / 36, cc = rem - rr * 36;
      int iy = IY0 + rr, ix = IX0 + cc;
      float v = 0.f;
      if (ok && cc < 35 && (unsigned)iy < 123u && (unsigned)ix < 123u)
        v = ib[(3 * phase + cil) * 15129 + iy * 123 + ix];
      if (ok) smem[idx] = v;
    }
    __syncthreads();
#pragma unroll
    for (int cil = 0; cil < 3; ++cil)
#pragma unroll
      for (int ky = 0; ky < 3; ++ky) {
        const float* xrow = &smem[(cil * 65 + 2 * r + ky) * 36 + 4 * seg];
        float xv[8];
#pragma unroll
        for (int j2 = 0; j2 < 4; ++j2) {   // 4x ds_read_b64
          float2 t2 = *reinterpret_cast<const float2*>(&xrow[2 * j2]);
          xv[2 * j2] = t2.x; xv[2 * j2 + 1] = t2.y;
        }
        const float* wp = wre2 + ((3 * phase + cil) * 3 + ky) * 45 + CO0;
        float wr[NCO * 3];
#pragma unroll
        for (int kx = 0; kx < 3; ++kx)
#pragma unroll
          for (int j = 0; j < NCO; ++j) wr[kx * NCO + j] = wp[kx * 15 + j];
#pragma unroll
        for (int c = 0; c < 2; ++c)
#pragma unroll
          for (int kx = 0; kx < 3; ++kx)
#pragma unroll
            for (int j = 0; j < NCO; ++j)
              acc[j][c] += xv[2 * c + kx] * wr[kx * NCO + j];
        if (seg == 7) {
#pragma unroll
          for (int kx = 0; kx < 3; ++kx)
#pragma unroll
            for (int j = 0; j < NCO; ++j)
              acc[j][2] += xv[4 + kx] * wr[kx * NCO + j];
        }
      }
  }
  __syncthreads();                         // xs reads done
  if (CY0 + r < 62) {
#pragma unroll
    for (int j = 0; j < NCO; ++j) {
      ct[j][r][2 * seg] = acc[j][0];
      ct[j][r][2 * seg + 1] = acc[j][1];
      if (seg == 7) ct[j][r][16] = acc[j][2];
    }
  }
  __syncthreads();
#pragma unroll
  for (int j = 0; j < NCO; ++j) {
    for (int i2 = tid; i2 < PRN * 16; i2 += 256) {
      int pr = i2 >> 4, pc = i2 & 15;
      int py = CY0 + pr, px = CX0 + pc;
      if (px < 61) {
        float m = fmaxf(fmaxf(ct[j][pr][pc], ct[j][pr][pc + 1]),
                        fmaxf(ct[j][pr + 1][pc], ct[j][pr + 1][pc + 1]));
        out[(size_t)b * 55815 + (CO0 + j) * 3721 + py * 61 + px] = fmaxf(m, 0.f);
      }
    }
  }
}

__global__ __launch_bounds__(256, 4) void k_conv2(const float* __restrict__ in,
                                                  const float* __restrict__ wre2,
                                                  const float* __restrict__ bia,
                                                  float* __restrict__ out) {
  __shared__ float smem[8160];                   // max(3*65*36=7020, 8*32*17=4352)
  int b = blockIdx.z;
  int ty_tile = blockIdx.y;                      // 0: conv rows 0..31, 1: 31..62
  int CY0 = ty_tile * 31;
  int CX0 = blockIdx.x * 16;
  int PRN = (ty_tile == 0) ? 31 : 30;
  int tid = threadIdx.x;
  int r = tid >> 3, seg = tid & 7;               // 32 rows x 8 segs
  const float* ib = in + (size_t)b * 90774;      // 6*123*123
  conv2_group<0, 8>(ib, wre2, bia, out, smem, b, CY0, CX0, PRN, r, seg, tid);
  conv2_group<8, 7>(ib, wre2, bia, out, smem, b, CY0, CX0, PRN, r, seg, tid);
}

// ---------------- fc1: (128,55815) x (120,55815)^T, split-K partials ----------------
#define KFC 55815
#define NCHUNK 1745  // ceil(55815/32)
#define FC1_BLOCKS 512
__global__ __launch_bounds__(256) void k_fc1(const float* __restrict__ h,
                                             const float* __restrict__ w,
                                             float* __restrict__ partial) {
  __shared__ float hs[128][33];   // +1 pad
  __shared__ float wsd[120][33];
  int tid = threadIdx.x;
  int tb = tid & 31;   // batch lane
  int bo = tid >> 5;   // output group: outputs bo*15 .. bo*15+14
  float acc[4][15];
#pragma unroll
  for (int j = 0; j < 4; ++j)
#pragma unroll
    for (int oo = 0; oo < 15; ++oo) acc[j][oo] = 0.f;

  for (int ch = blockIdx.x; ch < NCHUNK; ch += FC1_BLOCKS) {
    int k0 = ch * 32;
    for (int idx = tid; idx < 128 * 32; idx += 256) {
      int bb = idx >> 5, kk = idx & 31;
      int k = k0 + kk;
      hs[bb][kk] = (k < KFC) ? h[(size_t)bb * KFC + k] : 0.f;
    }
    for (int idx = tid; idx < 120 * 32; idx += 256) {
      int oo = idx >> 5, kk = idx & 31;
      int k = k0 + kk;
      wsd[oo][kk] = (k < KFC) ? w[(size_t)oo * KFC + k] : 0.f;
    }
    __syncthreads();
#pragma unroll 4
    for (int kk = 0; kk < 32; ++kk) {
      float hv[4], wv[15];
#pragma unroll
      for (int j = 0; j < 4; ++j) hv[j] = hs[tb + 32 * j][kk];
#pragma unroll
      for (int oo = 0; oo < 15; ++oo) wv[oo] = wsd[bo * 15 + oo][kk];
#pragma unroll
      for (int j = 0; j < 4; ++j)
#pragma unroll
        for (int oo = 0; oo < 15; ++oo) acc[j][oo] += hv[j] * wv[oo];
    }
    __syncthreads();
  }
  float* pg = partial + (size_t)blockIdx.x * 15360;
#pragma unroll
  for (int j = 0; j < 4; ++j) {
    int b = tb + 32 * j;
#pragma unroll
    for (int oo = 0; oo < 15; ++oo) pg[b * 120 + bo * 15 + oo] = acc[j][oo];
  }
}

__global__ __launch_bounds__(256) void k_fc1_reduce(const float* __restrict__ partial,
                                                    const float* __restrict__ bias,
                                                    float* __restrict__ outv) {
  int i = blockIdx.x * 256 + threadIdx.x;
  if (i >= 15360) return;
  float a = bias[i % 120];
  for (int g = 0; g < FC1_BLOCKS; ++g) a += partial[(size_t)g * 15360 + i];
  outv[i] = fmaxf(a, 0.f);  // relu fused
}

// ---------------- fc2 + fc3 + quantum head -> probs_conv ----------------
__global__ __launch_bounds__(128) void k_head(const float* __restrict__ fc1o,
                                              const float* __restrict__ w2,
                                              const float* __restrict__ b2,
                                              const float* __restrict__ w3,
                                              const float* __restrict__ b3,
                                              const float* __restrict__ hth,
                                              float* __restrict__ probs_conv) {
  __shared__ float h1[120];
  __shared__ float h2[84];
  int b = blockIdx.x, tid = threadIdx.x;
  if (tid < 120) h1[tid] = fc1o[b * 120 + tid];  // already relu'd
  __syncthreads();
  if (tid < 84) {
    float a = b2[tid];
    for (int k = 0; k < 120; ++k) a += h1[k] * w2[tid * 120 + k];
    h2[tid] = fmaxf(a, 0.f);
  }
  __syncthreads();
  if (tid == 0) {
    float lg = b3[0];
    for (int j = 0; j < 84; ++j) lg += h2[j] * w3[j];
    float s[16];
#pragma unroll
    for (int i = 0; i < 16; ++i) s[i] = 0.f;
    s[0] = 1.f;
    q_ry<0>(s, lg);
    q_layer(s, hth);
    float z = q_mz<0>(s);
    probs_conv[b] = 1.f / (1.f + expf(-z));
  }
}

// ---------------- resize 249->28 (jax linear+antialias), row pass ----------------
DEV void resize_win(int o, int& i0, int& i1, float& sf, float& inorm) {
  const float invs = 249.0f / 28.0f;
  sf = ((float)o + 0.5f) * invs - 0.5f;
  i0 = (int)ceilf(sf - invs); if (i0 < 0) i0 = 0;
  i1 = (int)floorf(sf + invs); if (i1 > 248) i1 = 248;
  float nrm = 0.f;
  for (int i = i0; i <= i1; ++i)
    nrm += fmaxf(0.f, 1.f - fabsf(sf - (float)i) * (28.0f / 249.0f));
  inorm = 1.f / nrm;
}

// tmp[b][oy][ix] = sum_iy W[oy][iy] * gray[b][iy][ix]
__global__ __launch_bounds__(256) void k_resize_rows(const float* __restrict__ x,
                                                     float* __restrict__ tmp) {
  int b = blockIdx.x / 28, oy = blockIdx.x % 28;
  int ix = threadIdx.x;
  if (ix >= 249) return;
  int i0, i1; float sf, inorm;
  resize_win(oy, i0, i1, sf, inorm);
  const float* xb = x + (size_t)b * 186003;
  float acc = 0.f;
  for (int iy = i0; iy <= i1; ++iy) {
    float wv = fmaxf(0.f, 1.f - fabsf(sf - (float)iy) * (28.0f / 249.0f)) * inorm;
    float gr = (xb[iy * 249 + ix] + xb[62001 + iy * 249 + ix] +
                xb[124002 + iy * 249 + ix]) * (1.0f / 3.0f);
    acc += wv * gr;
  }
  tmp[((size_t)b * 28 + oy) * 249 + ix] = acc;
}

// ---------------- col pass + patches + per-patch circuits + lin + combine ----------------
__global__ __launch_bounds__(256) void k_quanv(const float* __restrict__ tmp,
                                               const float* __restrict__ qth,
                                               const float* __restrict__ lw,
                                               const float* __restrict__ lb,
                                               const float* __restrict__ probs_conv,
                                               float* __restrict__ out) {
  __shared__ float g[784];
  __shared__ float red[4];
  int b = blockIdx.x, tid = threadIdx.x;
  for (int idx = tid; idx < 784; idx += 256) {
    int oy = idx / 28, ox = idx % 28;
    int i0, i1; float sf, inorm;
    resize_win(ox, i0, i1, sf, inorm);
    const float* tr = tmp + ((size_t)b * 28 + oy) * 249;
    float acc = 0.f;
    for (int i = i0; i <= i1; ++i)
      acc += fmaxf(0.f, 1.f - fabsf(sf - (float)i) * (28.0f / 249.0f)) * inorm * tr[i];
    g[idx] = acc;
  }
  __syncthreads();
  float part = 0.f;
  if (tid < 196) {
    int pi = tid / 14, pj = tid % 14;
    float v0 = g[(2 * pi) * 28 + 2 * pj];
    float v1 = g[(2 * pi) * 28 + 2 * pj + 1];
    float v2 = g[(2 * pi + 1) * 28 + 2 * pj];
    float v3 = g[(2 * pi + 1) * 28 + 2 * pj + 1];
    float s[16];
#pragma unroll
    for (int i = 0; i < 16; ++i) s[i] = 0.f;
    s[0] = 1.f;
    q_ry<0>(s, v0); q_ry<1>(s, v1); q_ry<2>(s, v2); q_ry<3>(s, v3);
    q_layer(s, qth);
    float z0 = q_mz<0>(s), z1 = q_mz<1>(s), z2 = q_mz<2>(s), z3 = q_mz<3>(s);
    const float* lwp = lw + tid * 4;
    part = z0 * lwp[0] + z1 * lwp[1] + z2 * lwp[2] + z3 * lwp[3];
  }
#pragma unroll
  for (int off = 32; off > 0; off >>= 1) part += __shfl_down(part, off, 64);
  if ((tid & 63) == 0) red[tid >> 6] = part;
  __syncthreads();
  if (tid == 0) {
    float tot = red[0] + red[1] + red[2] + red[3] + lb[0];
    float pq = 1.f / (1.f + expf(-tot));
    float pr = 0.5f * (probs_conv[b] + pq);
    out[b * 2 + 0] = pr;
    out[b * 2 + 1] = 1.f - pr;
  }
}

// ---------------- launch ----------------
extern "C" void kernel_launch(void* const* d_in, const int* in_sizes, int n_in,
                              void* d_out, int out_size, void* d_ws, size_t ws_size,
                              hipStream_t stream) {
  const float* x   = (const float*)d_in[0];
  const float* c1w = (const float*)d_in[1];
  const float* c1b = (const float*)d_in[2];
  const float* c2w = (const float*)d_in[3];
  const float* c2b = (const float*)d_in[4];
  const float* f1w = (const float*)d_in[5];
  const float* f1b = (const float*)d_in[6];
  const float* f2w = (const float*)d_in[7];
  const float* f2b = (const float*)d_in[8];
  const float* f3w = (const float*)d_in[9];
  const float* f3b = (const float*)d_in[10];
  const float* hth = (const float*)d_in[11];
  const float* qth = (const float*)d_in[12];
  const float* lw  = (const float*)d_in[13];
  const float* lb  = (const float*)d_in[14];
  float* out = (float*)d_out;
  char* ws = (char*)d_ws;

  float* pool1   = (float*)(ws);
  float* partial = pool1;  // pool1 dead after k_conv2; 512*15360*4 = 31.5MB
  float* h       = (float*)(ws + 46476288);
  float* tmp     = (float*)(ws + 75053568);
  float* fc1o    = (float*)(ws + 78623232);
  float* pconv   = (float*)(ws + 78684672);
  float* wre1    = (float*)(ws + 78685184);  // 450 floats
  float* wre2    = (float*)(ws + 78686984);  // 810 floats

  k_wre<<<dim3(4), 256, 0, stream>>>(c1w, c2w, wre1, wre2);
  k_conv1<<<dim3(8, 3, 128), 256, 0, stream>>>(x, wre1, c1b, pool1);
  k_conv2<<<dim3(4, 2, 128), 256, 0, stream>>>(pool1, wre2, c2b, h);
  k_fc1<<<dim3(FC1_BLOCKS), 256, 0, stream>>>(h, f1w, partial);
  k_fc1_reduce<<<dim3(60), 256, 0, stream>>>(partial, f1b, fc1o);
  k_head<<<dim3(128), 128, 0, stream>>>(fc1o, f2w, f2b, f3w, f3b, hth, pconv);
  k_resize_rows<<<dim3(128 * 28), 256, 0, stream>>>(x, tmp);
  k_quanv<<<dim3(128), 256, 0, stream>>>(tmp, qth, lw, lb, pconv, out);
}

// Round 12
// 265.868 us; speedup vs baseline: 2.1079x; 2.1079x over previous
//
#include <hip/hip_runtime.h>
#include <math.h>

#define DEV static __device__ __forceinline__

// ---------------- 4-qubit real-amplitude circuit helpers ----------------
template <int W>
DEV void q_ry(float s[16], float th) {
  float c = cosf(th * 0.5f), sn = sinf(th * 0.5f);
  constexpr int m = 8 >> W;
#pragma unroll
  for (int i = 0; i < 16; ++i) {
    if (!(i & m)) {
      float a = s[i], b = s[i | m];
      s[i] = c * a - sn * b;
      s[i | m] = sn * a + c * b;
    }
  }
}
template <int C, int T>
DEV void q_cnot(float s[16]) {
  constexpr int mc = 8 >> C, mt = 8 >> T;
#pragma unroll
  for (int i = 0; i < 16; ++i) {
    if ((i & mc) && !(i & mt)) {
      float t = s[i]; s[i] = s[i | mt]; s[i | mt] = t;
    }
  }
}
template <int W>
DEV float q_mz(const float s[16]) {
  constexpr int m = 8 >> W;
  float p = 0.f;
#pragma unroll
  for (int i = 0; i < 16; ++i) p += (i & m) ? -s[i] * s[i] : s[i] * s[i];
  return p;
}
DEV void q_layer(float s[16], const float* __restrict__ th) {
  q_ry<0>(s, th[0]); q_cnot<0, 1>(s);
  q_ry<1>(s, th[1]); q_cnot<1, 2>(s);
  q_ry<2>(s, th[2]); q_cnot<2, 3>(s);
  q_ry<3>(s, th[3]); q_cnot<3, 0>(s);
}

// ---------------- weight reorder pre-kernel (conv1 only) ----------------
// wre1[(ci*5+ky)*30 + kx*6 + co] = c1w[co][ci][ky][kx]   (450)
__global__ void k_wre(const float* __restrict__ c1w, float* __restrict__ wre1) {
  int t = blockIdx.x * 256 + threadIdx.x;
  if (t < 450) {
    int g = t / 30, rem = t % 30;
    int ci = g / 5, ky = g % 5, kx = rem / 6, co = rem % 6;
    wre1[t] = c1w[co * 75 + ci * 25 + ky * 5 + kx];
  }
}

// ---------------- conv1 (5x5 s2 p1, 3->6) + relu + pool(2x2 s1) ----------------
// v6 + padded output rows (128 floats -> aligned 64B stores, unconditional).
// x: (128,3,249,249) -> pooled out: (128,6,123,[128])
__global__ __launch_bounds__(256, 4) void k_conv1(const float* __restrict__ x,
                                                  const float* __restrict__ wre1,
                                                  const float* __restrict__ bia,
                                                  float* __restrict__ out) {
  __shared__ float smem[9920];                   // 3*87*38 + pad = 39.7 KB
  float (*ct)[42][19] = (float (*)[42][19])smem; // conv-subtile view (aliases xs)
  int b = blockIdx.z;
  int PY0 = blockIdx.y * 41, PX0 = blockIdx.x * 16;
  int iy0 = PY0 * 2 - 1, ix0 = PX0 * 2 - 1;
  int tid = threadIdx.x;
  const float* xb = x + (size_t)b * 186003;  // 3*249*249
#pragma unroll
  for (int s = 0; s < 39; ++s) {
    int idx = s * 256 + tid;
    bool ok = idx < 9918;
    int ci = idx / 3306, rem = idx - ci * 3306;
    int rr = rem / 38, cc = rem - rr * 38;
    int iy = iy0 + rr, ix = ix0 + cc;
    float v = 0.f;
    if (ok && cc < 37 && (unsigned)iy < 249u && (unsigned)ix < 249u)
      v = xb[ci * 62001 + iy * 249 + ix];
    if (ok) smem[idx] = v;
  }
  __syncthreads();
  int r = tid / 6, seg = tid - 6 * (tid / 6);   // 42 rows x 6 segs = 252
  float acc[6][3];
  if (tid < 252) {
#pragma unroll
    for (int co = 0; co < 6; ++co) {
      float bv = bia[co];
#pragma unroll
      for (int c = 0; c < 3; ++c) acc[co][c] = bv;
    }
#pragma unroll
    for (int ci = 0; ci < 3; ++ci)
#pragma unroll
      for (int ky = 0; ky < 5; ++ky) {
        const float* xrow = &smem[(ci * 87 + 2 * r + ky) * 38 + 6 * seg];
        float xv[10];
#pragma unroll
        for (int j = 0; j < 5; ++j) {            // 5x ds_read_b64
          float2 t2 = *reinterpret_cast<const float2*>(&xrow[2 * j]);
          xv[2 * j] = t2.x; xv[2 * j + 1] = t2.y;
        }
        const float* wp = wre1 + (ci * 5 + ky) * 30;  // uniform -> s_load
        float wr[30];
#pragma unroll
        for (int j = 0; j < 30; ++j) wr[j] = wp[j];
#pragma unroll
        for (int c = 0; c < 3; ++c)
#pragma unroll
          for (int kx = 0; kx < 5; ++kx)
#pragma unroll
            for (int co = 0; co < 6; ++co)
              acc[co][c] += xv[2 * c + kx] * wr[kx * 6 + co];
      }
  }
  __syncthreads();                          // xs reads complete
  if (tid < 252) {
#pragma unroll
    for (int co = 0; co < 6; ++co)
#pragma unroll
      for (int c = 0; c < 3; ++c)
        if (3 * seg + c < 17) ct[co][r][3 * seg + c] = acc[co][c];
  }
  __syncthreads();
  // pool+store: 16 consecutive lanes -> aligned 64B; rows padded to 128
#pragma unroll
  for (int co2 = 0; co2 < 6; ++co2) {
    for (int j = tid; j < 41 * 16; j += 256) {
      int pr = j >> 4, pc = j & 15;
      float m = fmaxf(fmaxf(ct[co2][pr][pc], ct[co2][pr][pc + 1]),
                      fmaxf(ct[co2][pr + 1][pc], ct[co2][pr + 1][pc + 1]));
      out[((size_t)(b * 6 + co2) * 123 + PY0 + pr) * 128 + PX0 + pc] = fmaxf(m, 0.f);
    }
  }
}

// ---------------- conv2 (3x3 s2 p1, 6->15) + relu + pool ----------------
// round-9 v2 (proven): co=tid%15 broadcast rows, stride-36 float2 reads,
// wreg[9]/ci, xs/ct aliased (30.2KB). Input rows padded to 128.
// in: (128,6,123,[128]) -> h: (128, 15*61*61=55815)
__global__ __launch_bounds__(256, 4) void k_conv2(const float* __restrict__ in,
                                                  const float* __restrict__ w,
                                                  const float* __restrict__ bia,
                                                  float* __restrict__ out) {
  __shared__ float smem[6 * 35 * 36];            // 7560 words = 30.2 KB
  float (*xs)[35][36] = (float (*)[35][36])smem; // staging view
  float (*ct)[17][18] = (float (*)[17][18])smem; // conv-subtile view (aliased)
  int b = blockIdx.z;
  int py0 = blockIdx.y * 16, px0 = blockIdx.x * 16;
  int iy0 = py0 * 2 - 1, ix0 = px0 * 2 - 1;
  int tid = threadIdx.x;
  const float* ib = in + (size_t)b * 94464;  // 6*123*128
  for (int idx = tid; idx < 6 * 35 * 36; idx += 256) {
    int ci = idx / 1260, rem = idx % 1260, rr = rem / 36, cc = rem % 36;
    int iy = iy0 + rr, ix = ix0 + cc;
    float v = 0.f;
    if (cc < 35 && (unsigned)iy < 123u && (unsigned)ix < 123u)
      v = ib[ci * 15744 + iy * 128 + ix];
    xs[ci][rr][cc] = v;
  }
  __syncthreads();
  int co = tid % 15, ty = tid / 15;        // 15 lanes/row-group -> broadcast
  float acc[17];
  if (tid < 255) {
    float bv = bia[co];
#pragma unroll
    for (int t = 0; t < 17; ++t) acc[t] = bv;
#pragma unroll
    for (int ci = 0; ci < 6; ++ci) {
      float wreg[9];
#pragma unroll
      for (int j = 0; j < 9; ++j) wreg[j] = w[co * 54 + ci * 9 + j];
#pragma unroll
      for (int ky = 0; ky < 3; ++ky) {
        const float* xrow = &xs[ci][2 * ty + ky][0];  // 8B-aligned (stride 36)
        float xv[36];
#pragma unroll
        for (int j = 0; j < 18; ++j) {                // 18x ds_read_b64
          float2 t2 = *reinterpret_cast<const float2*>(&xrow[2 * j]);
          xv[2 * j] = t2.x; xv[2 * j + 1] = t2.y;
        }
#pragma unroll
        for (int tx = 0; tx < 17; ++tx)
#pragma unroll
          for (int kx = 0; kx < 3; ++kx)
            acc[tx] += xv[2 * tx + kx] * wreg[ky * 3 + kx];
      }
    }
  }
  __syncthreads();                         // all xs reads complete
  if (tid < 255) {
#pragma unroll
    for (int tx = 0; tx < 17; ++tx) ct[co][ty][tx] = acc[tx];  // alias write
  }
  __syncthreads();
  // coalesced pool+store
  for (int i = tid; i < 15 * 16 * 16; i += 256) {
    int co2 = i / 256, rem = i % 256, pr = rem / 16, pc = rem % 16;
    int py = py0 + pr, px = px0 + pc;
    if (py < 61 && px < 61) {
      float m = fmaxf(fmaxf(ct[co2][pr][pc], ct[co2][pr][pc + 1]),
                      fmaxf(ct[co2][pr + 1][pc], ct[co2][pr + 1][pc + 1]));
      out[(size_t)b * 55815 + co2 * 3721 + py * 61 + px] = fmaxf(m, 0.f);
    }
  }
}

// ---------------- fc1: (128,55815) x (120,55815)^T, split-K partials ----------------
#define KFC 55815
#define NCHUNK 1745  // ceil(55815/32)
#define FC1_BLOCKS 512
__global__ __launch_bounds__(256) void k_fc1(const float* __restrict__ h,
                                             const float* __restrict__ w,
                                             float* __restrict__ partial) {
  __shared__ float hs[128][33];   // +1 pad
  __shared__ float wsd[120][33];
  int tid = threadIdx.x;
  int tb = tid & 31;   // batch lane
  int bo = tid >> 5;   // output group: outputs bo*15 .. bo*15+14
  float acc[4][15];
#pragma unroll
  for (int j = 0; j < 4; ++j)
#pragma unroll
    for (int oo = 0; oo < 15; ++oo) acc[j][oo] = 0.f;

  for (int ch = blockIdx.x; ch < NCHUNK; ch += FC1_BLOCKS) {
    int k0 = ch * 32;
    for (int idx = tid; idx < 128 * 32; idx += 256) {
      int bb = idx >> 5, kk = idx & 31;
      int k = k0 + kk;
      hs[bb][kk] = (k < KFC) ? h[(size_t)bb * KFC + k] : 0.f;
    }
    for (int idx = tid; idx < 120 * 32; idx += 256) {
      int oo = idx >> 5, kk = idx & 31;
      int k = k0 + kk;
      wsd[oo][kk] = (k < KFC) ? w[(size_t)oo * KFC + k] : 0.f;
    }
    __syncthreads();
#pragma unroll 4
    for (int kk = 0; kk < 32; ++kk) {
      float hv[4], wv[15];
#pragma unroll
      for (int j = 0; j < 4; ++j) hv[j] = hs[tb + 32 * j][kk];
#pragma unroll
      for (int oo = 0; oo < 15; ++oo) wv[oo] = wsd[bo * 15 + oo][kk];
#pragma unroll
      for (int j = 0; j < 4; ++j)
#pragma unroll
        for (int oo = 0; oo < 15; ++oo) acc[j][oo] += hv[j] * wv[oo];
    }
    __syncthreads();
  }
  float* pg = partial + (size_t)blockIdx.x * 15360;
#pragma unroll
  for (int j = 0; j < 4; ++j) {
    int b = tb + 32 * j;
#pragma unroll
    for (int oo = 0; oo < 15; ++oo) pg[b * 120 + bo * 15 + oo] = acc[j][oo];
  }
}

__global__ __launch_bounds__(256) void k_fc1_reduce(const float* __restrict__ partial,
                                                    const float* __restrict__ bias,
                                                    float* __restrict__ outv) {
  int i = blockIdx.x * 256 + threadIdx.x;
  if (i >= 15360) return;
  float a = bias[i % 120];
  for (int g = 0; g < FC1_BLOCKS; ++g) a += partial[(size_t)g * 15360 + i];
  outv[i] = fmaxf(a, 0.f);  // relu fused
}

// ---------------- fc2 + fc3 + quantum head -> probs_conv ----------------
__global__ __launch_bounds__(128) void k_head(const float* __restrict__ fc1o,
                                              const float* __restrict__ w2,
                                              const float* __restrict__ b2,
                                              const float* __restrict__ w3,
                                              const float* __restrict__ b3,
                                              const float* __restrict__ hth,
                                              float* __restrict__ probs_conv) {
  __shared__ float h1[120];
  __shared__ float h2[84];
  int b = blockIdx.x, tid = threadIdx.x;
  if (tid < 120) h1[tid] = fc1o[b * 120 + tid];  // already relu'd
  __syncthreads();
  if (tid < 84) {
    float a = b2[tid];
    for (int k = 0; k < 120; ++k) a += h1[k] * w2[tid * 120 + k];
    h2[tid] = fmaxf(a, 0.f);
  }
  __syncthreads();
  if (tid == 0) {
    float lg = b3[0];
    for (int j = 0; j < 84; ++j) lg += h2[j] * w3[j];
    float s[16];
#pragma unroll
    for (int i = 0; i < 16; ++i) s[i] = 0.f;
    s[0] = 1.f;
    q_ry<0>(s, lg);
    q_layer(s, hth);
    float z = q_mz<0>(s);
    probs_conv[b] = 1.f / (1.f + expf(-z));
  }
}

// ---------------- resize 249->28 (jax linear+antialias), row pass ----------------
DEV void resize_win(int o, int& i0, int& i1, float& sf, float& inorm) {
  const float invs = 249.0f / 28.0f;
  sf = ((float)o + 0.5f) * invs - 0.5f;
  i0 = (int)ceilf(sf - invs); if (i0 < 0) i0 = 0;
  i1 = (int)floorf(sf + invs); if (i1 > 248) i1 = 248;
  float nrm = 0.f;
  for (int i = i0; i <= i1; ++i)
    nrm += fmaxf(0.f, 1.f - fabsf(sf - (float)i) * (28.0f / 249.0f));
  inorm = 1.f / nrm;
}

// tmp[b][oy][ix] = sum_iy W[oy][iy] * gray[b][iy][ix]
__global__ __launch_bounds__(256) void k_resize_rows(const float* __restrict__ x,
                                                     float* __restrict__ tmp) {
  int b = blockIdx.x / 28, oy = blockIdx.x % 28;
  int ix = threadIdx.x;
  if (ix >= 249) return;
  int i0, i1; float sf, inorm;
  resize_win(oy, i0, i1, sf, inorm);
  const float* xb = x + (size_t)b * 186003;
  float acc = 0.f;
  for (int iy = i0; iy <= i1; ++iy) {
    float wv = fmaxf(0.f, 1.f - fabsf(sf - (float)iy) * (28.0f / 249.0f)) * inorm;
    float gr = (xb[iy * 249 + ix] + xb[62001 + iy * 249 + ix] +
                xb[124002 + iy * 249 + ix]) * (1.0f / 3.0f);
    acc += wv * gr;
  }
  tmp[((size_t)b * 28 + oy) * 249 + ix] = acc;
}

// ---------------- col pass + patches + circuits: 2 blocks per batch ----------------
// block = (b, half): computes g rows [14*half, 14*half+14) and patch rows
// [7*half, 7*half+7); writes partial linear sum to qpart[bid].
__global__ __launch_bounds__(256) void k_quanv(const float* __restrict__ tmp,
                                               const float* __restrict__ qth,
                                               const float* __restrict__ lw,
                                               float* __restrict__ qpart) {
  __shared__ float g[392];
  __shared__ float red[4];
  int bid = blockIdx.x;
  int b = bid >> 1, half = bid & 1;
  int tid = threadIdx.x;
  for (int idx = tid; idx < 392; idx += 256) {
    int ly = idx / 28, ox = idx % 28;
    int oy = 14 * half + ly;
    int i0, i1; float sf, inorm;
    resize_win(ox, i0, i1, sf, inorm);
    const float* tr = tmp + ((size_t)b * 28 + oy) * 249;
    float acc = 0.f;
    for (int i = i0; i <= i1; ++i)
      acc += fmaxf(0.f, 1.f - fabsf(sf - (float)i) * (28.0f / 249.0f)) * inorm * tr[i];
    g[idx] = acc;
  }
  __syncthreads();
  float part = 0.f;
  if (tid < 98) {
    int pl = tid / 14, pj = tid % 14;        // local patch row 0..6
    int pi = 7 * half + pl;                  // global patch row
    float v0 = g[(2 * pl) * 28 + 2 * pj];
    float v1 = g[(2 * pl) * 28 + 2 * pj + 1];
    float v2 = g[(2 * pl + 1) * 28 + 2 * pj];
    float v3 = g[(2 * pl + 1) * 28 + 2 * pj + 1];
    float s[16];
#pragma unroll
    for (int i = 0; i < 16; ++i) s[i] = 0.f;
    s[0] = 1.f;
    q_ry<0>(s, v0); q_ry<1>(s, v1); q_ry<2>(s, v2); q_ry<3>(s, v3);
    q_layer(s, qth);
    float z0 = q_mz<0>(s), z1 = q_mz<1>(s), z2 = q_mz<2>(s), z3 = q_mz<3>(s);
    const float* lwp = lw + (pi * 14 + pj) * 4;
    part = z0 * lwp[0] + z1 * lwp[1] + z2 * lwp[2] + z3 * lwp[3];
  }
#pragma unroll
  for (int off = 32; off > 0; off >>= 1) part += __shfl_down(part, off, 64);
  if ((tid & 63) == 0) red[tid >> 6] = part;
  __syncthreads();
  if (tid == 0) qpart[bid] = red[0] + red[1] + red[2] + red[3];
}

// ---------------- finalize: combine halves + sigmoid + output ----------------
__global__ __launch_bounds__(128) void k_final(const float* __restrict__ qpart,
                                               const float* __restrict__ lb,
                                               const float* __restrict__ probs_conv,
                                               float* __restrict__ out) {
  int b = threadIdx.x;
  float tot = qpart[2 * b] + qpart[2 * b + 1] + lb[0];
  float pq = 1.f / (1.f + expf(-tot));
  float pr = 0.5f * (probs_conv[b] + pq);
  out[b * 2 + 0] = pr;
  out[b * 2 + 1] = 1.f - pr;
}

// ---------------- launch ----------------
extern "C" void kernel_launch(void* const* d_in, const int* in_sizes, int n_in,
                              void* d_out, int out_size, void* d_ws, size_t ws_size,
                              hipStream_t stream) {
  const float* x   = (const float*)d_in[0];
  const float* c1w = (const float*)d_in[1];
  const float* c1b = (const float*)d_in[2];
  const float* c2w = (const float*)d_in[3];
  const float* c2b = (const float*)d_in[4];
  const float* f1w = (const float*)d_in[5];
  const float* f1b = (const float*)d_in[6];
  const float* f2w = (const float*)d_in[7];
  const float* f2b = (const float*)d_in[8];
  const float* f3w = (const float*)d_in[9];
  const float* f3b = (const float*)d_in[10];
  const float* hth = (const float*)d_in[11];
  const float* qth = (const float*)d_in[12];
  const float* lw  = (const float*)d_in[13];
  const float* lb  = (const float*)d_in[14];
  float* out = (float*)d_out;
  char* ws = (char*)d_ws;

  // ws layout (bytes):
  //   [0, 48365568)            pool1 (128*6*123*128 f32, padded rows)
  //     after conv2, region reused:
  //       [0, 31457280)        fc1 partials (512*15360 f32)
  //       [33554432, 37124096) tmp resize rows (128*28*249 f32)
  //   [48365568, 76942848)     h (128*55815 f32)
  //   [76942848, 77004288)     fc1o
  //   [77004288, 77004800)     pconv
  //   [77004800, 77006600)     wre1
  //   [77009848, 77010872)     qpart (256 f32)
  float* pool1   = (float*)(ws);
  float* partial = (float*)(ws);
  float* tmp     = (float*)(ws + 33554432);
  float* h       = (float*)(ws + 48365568);
  float* fc1o    = (float*)(ws + 76942848);
  float* pconv   = (float*)(ws + 77004288);
  float* wre1    = (float*)(ws + 77004800);
  float* qpart   = (float*)(ws + 77009848);

  k_wre<<<dim3(2), 256, 0, stream>>>(c1w, wre1);
  k_conv1<<<dim3(8, 3, 128), 256, 0, stream>>>(x, wre1, c1b, pool1);
  k_conv2<<<dim3(4, 4, 128), 256, 0, stream>>>(pool1, c2w, c2b, h);
  k_fc1<<<dim3(FC1_BLOCKS), 256, 0, stream>>>(h, f1w, partial);
  k_fc1_reduce<<<dim3(60), 256, 0, stream>>>(partial, f1b, fc1o);
  k_head<<<dim3(128), 128, 0, stream>>>(fc1o, f2w, f2b, f3w, f3b, hth, pconv);
  k_resize_rows<<<dim3(128 * 28), 256, 0, stream>>>(x, tmp);
  k_quanv<<<dim3(256), 256, 0, stream>>>(tmp, qth, lw, qpart);
  k_final<<<dim3(1), 128, 0, stream>>>(qpart, lb, pconv, out);
}